// Round 5
// baseline (621.555 us; speedup 1.0000x reference)
//
#include <hip/hip_runtime.h>
#include <math.h>

#define NE   2048
#define FEAT 512

typedef short short8 __attribute__((ext_vector_type(8)));
typedef float f32x4  __attribute__((ext_vector_type(4)));

__device__ __forceinline__ unsigned short f2bf(float f) {
    union { float f; unsigned u; } v; v.f = f;
    unsigned r = v.u + 0x7fffu + ((v.u >> 16) & 1u);   // RNE
    return (unsigned short)(r >> 16);
}
__device__ __forceinline__ float bf2f(unsigned b) {
    union { unsigned u; float f; } v; v.u = b << 16;
    return v.f;
}
__device__ __forceinline__ unsigned pack2(float a, float b) {
    return (unsigned)f2bf(a) | ((unsigned)f2bf(b) << 16);
}

// ---------------------------------------------------------------------------
// K0: x[n][f][r] fp32 -> xt[(n*8+r)][f] bf16
// ---------------------------------------------------------------------------
__global__ __launch_bounds__(256) void xpose_kernel(const float* __restrict__ x,
                                                    unsigned short* __restrict__ xt)
{
    __shared__ float xs[8 * 516];
    const int t = threadIdx.x;
    const int n = blockIdx.x;
    const float4* xp = (const float4*)(x + (size_t)n * 4096);
    #pragma unroll
    for (int i = 0; i < 4; ++i) {
        int idx = t + 256 * i;
        float4 v = xp[idx];
        int f = idx >> 1, rh = (idx & 1) * 4;
        xs[(rh + 0) * 516 + f] = v.x;
        xs[(rh + 1) * 516 + f] = v.y;
        xs[(rh + 2) * 516 + f] = v.z;
        xs[(rh + 3) * 516 + f] = v.w;
    }
    __syncthreads();
    const int r = t >> 5, f0 = (t & 31) * 16;
    const float* src = &xs[r * 516 + f0];
    unsigned o[8];
    #pragma unroll
    for (int j = 0; j < 8; ++j) o[j] = pack2(src[2 * j], src[2 * j + 1]);
    unsigned short* dst = xt + (size_t)n * 4096 + r * 512 + f0;
    *(uint4*)dst       = make_uint4(o[0], o[1], o[2], o[3]);
    *(uint4*)(dst + 8) = make_uint4(o[4], o[5], o[6], o[7]);
}

// ---------------------------------------------------------------------------
// K1: proj GEMM. w=0/1 -> qb/kb [h][n][f] bf16 (coalesced LDS-bounce).
// w=2 -> dTu [h][f][m] bf16 (transposed write, unscaled).
// Also accumulates per-n sumsq (from bf16 values) into ssq[w][n] via atomics.
// ---------------------------------------------------------------------------
__global__ __launch_bounds__(256) void proj_gemm(
    const float* __restrict__ Wq, const float* __restrict__ Wk, const float* __restrict__ Wd,
    const unsigned short* __restrict__ xt,
    unsigned short* __restrict__ qb, unsigned short* __restrict__ kb,
    unsigned short* __restrict__ dTu, float* __restrict__ ssq)
{
    __shared__ unsigned short smem[2 * 128 * 72];   // As | Bs, re-used as C-tile
    __shared__ float ssl[16];
    unsigned short* As = smem;
    unsigned short* Bs = smem + 128 * 72;
    unsigned short* Cs = smem;                      // 128 x 136 bf16

    const int t = threadIdx.x;
    const int w = blockIdx.z;
    const float* W = (w == 0) ? Wq : (w == 1) ? Wk : Wd;
    const int M0 = blockIdx.y * 128;
    const int N0 = blockIdx.x * 128;
    const int wave = t >> 6, lane = t & 63;
    const int quad = lane >> 4, l16 = lane & 15;

    f32x4 acc[2][8];
    #pragma unroll
    for (int i = 0; i < 2; ++i)
        #pragma unroll
        for (int j = 0; j < 8; ++j) acc[i][j] = {0.f, 0.f, 0.f, 0.f};

    const int ar = t >> 2, afs = (t & 3) * 16;
    const int br = t >> 3, bcs = (t & 7) * 8;

    for (int kc = 0; kc < 8; ++kc) {
        #pragma unroll
        for (int p = 0; p < 2; ++p) {
            int row = ar + p * 64;
            const float4* g = (const float4*)(W + (size_t)(M0 + row) * 512 + kc * 64 + afs);
            float4 v0 = g[0], v1 = g[1], v2 = g[2], v3 = g[3];
            unsigned short* d = &As[row * 72 + afs];
            *(uint4*)d       = make_uint4(pack2(v0.x, v0.y), pack2(v0.z, v0.w),
                                          pack2(v1.x, v1.y), pack2(v1.z, v1.w));
            *(uint4*)(d + 8) = make_uint4(pack2(v2.x, v2.y), pack2(v2.z, v2.w),
                                          pack2(v3.x, v3.y), pack2(v3.z, v3.w));
        }
        #pragma unroll
        for (int p = 0; p < 4; ++p) {
            int row = br + p * 32;
            *(uint4*)&Bs[row * 72 + bcs] =
                *(const uint4*)(xt + (size_t)(N0 + row) * 512 + kc * 64 + bcs);
        }
        __syncthreads();
        #pragma unroll
        for (int kk = 0; kk < 2; ++kk) {
            short8 a0 = *(const short8*)&As[(wave * 32 + l16) * 72 + kk * 32 + quad * 8];
            short8 a1 = *(const short8*)&As[(wave * 32 + 16 + l16) * 72 + kk * 32 + quad * 8];
            #pragma unroll
            for (int ct = 0; ct < 8; ++ct) {
                short8 b = *(const short8*)&Bs[(ct * 16 + l16) * 72 + kk * 32 + quad * 8];
                acc[0][ct] = __builtin_amdgcn_mfma_f32_16x16x32_bf16(a0, b, acc[0][ct], 0, 0, 0);
                acc[1][ct] = __builtin_amdgcn_mfma_f32_16x16x32_bf16(a1, b, acc[1][ct], 0, 0, 0);
            }
        }
        __syncthreads();
    }
    // ---- C-tile -> LDS (bf16) ----
    #pragma unroll
    for (int rt = 0; rt < 2; ++rt)
        #pragma unroll
        for (int reg = 0; reg < 4; ++reg) {
            int rloc = wave * 32 + rt * 16 + quad * 4 + reg;
            #pragma unroll
            for (int ct = 0; ct < 8; ++ct)
                Cs[rloc * 136 + ct * 16 + l16] = f2bf(acc[rt][ct][reg]);
        }
    if (t < 16) ssl[t] = 0.f;
    __syncthreads();

    const int h0 = blockIdx.y * 2, n0g = blockIdx.x * 16;
    const int hn = t >> 3, lg = t & 7;
    const int hh = hn >> 4, nn = hn & 15;
    float ssloc = 0.f;

    if (w < 2) {
        unsigned short* out = (w == 0) ? qb : kb;
        unsigned short* dst = out + ((size_t)(h0 + hh) * NE + n0g + nn) * 512 + lg * 64;
        #pragma unroll
        for (int li = 0; li < 8; ++li) {
            uint4 v = *(const uint4*)&Cs[(hh * 64 + lg * 8 + li) * 136 + nn * 8];
            *(uint4*)(dst + li * 8) = v;
            unsigned a[4] = {v.x, v.y, v.z, v.w};
            #pragma unroll
            for (int j = 0; j < 4; ++j) {
                float lo = bf2f(a[j] & 0xffffu), hi = bf2f(a[j] >> 16);
                ssloc += lo * lo + hi * hi;
            }
        }
    } else {
        #pragma unroll
        for (int li = 0; li < 8; ++li) {
            uint4 v = *(const uint4*)&Cs[(hh * 64 + lg * 8 + li) * 136 + nn * 8];
            unsigned a[4] = {v.x, v.y, v.z, v.w};
            #pragma unroll
            for (int j = 0; j < 4; ++j) {
                float lo = bf2f(a[j] & 0xffffu), hi = bf2f(a[j] >> 16);
                ssloc += lo * lo + hi * hi;
            }
        }
        // transposed write: dTu[h][l*8+r][m], 16 m per block (2 x uint4)
        #pragma unroll
        for (int i = 0; i < 4; ++i) {
            int pos = t + 256 * i;
            int hh2 = pos >> 9, l = (pos >> 3) & 63, r = pos & 7;
            const unsigned short* crow = &Cs[(hh2 * 64 + l) * 136 + r];
            unsigned o[8];
            #pragma unroll
            for (int j = 0; j < 8; ++j)
                o[j] = (unsigned)crow[(2 * j) * 8] | ((unsigned)crow[(2 * j + 1) * 8] << 16);
            unsigned short* dp = dTu + ((size_t)(h0 + hh2) * 512 + l * 8 + r) * NE + n0g;
            *(uint4*)dp       = make_uint4(o[0], o[1], o[2], o[3]);
            *(uint4*)(dp + 8) = make_uint4(o[4], o[5], o[6], o[7]);
        }
    }
    atomicAdd(&ssl[nn], ssloc);
    __syncthreads();
    if (t < 16) atomicAdd(&ssq[w * NE + n0g + t], ssl[t]);
}

// ---------------------------------------------------------------------------
// K2a: scores -> exp -> P' = e * rsqrt(dss[m]) bf16 (coalesced), l-sums to lbuf.
// Register-prefetch of next K-chunk; single LDS buffer (keeps 4 blocks/CU).
// |s|<=1 (unit vectors) so no max subtraction.
// ---------------------------------------------------------------------------
__global__ __launch_bounds__(256) void score_kernel(
    const unsigned short* __restrict__ qb, const unsigned short* __restrict__ kb,
    const float* __restrict__ ssq, unsigned short* __restrict__ P,
    float* __restrict__ lbuf, int g)
{
    __shared__ unsigned short smem[2 * 128 * 72];   // As | Bs, re-used as P-tile
    unsigned short* As = smem;
    unsigned short* Bs = smem + 128 * 72;
    unsigned short* Pl = smem;                      // 128 x 136 bf16

    const int t = threadIdx.x;
    const int hg = blockIdx.z, h = g * 4 + hg;
    const int n0 = blockIdx.y * 128, m0 = blockIdx.x * 128;
    const int wave = t >> 6, lane = t & 63, quad = lane >> 4, l16 = lane & 15;
    const unsigned short* qh = qb + (size_t)h * NE * 512;
    const unsigned short* kh = kb + (size_t)h * NE * 512;
    const int br = t >> 3, bcs = (t & 7) * 8;

    f32x4 acc[2][8];
    #pragma unroll
    for (int i = 0; i < 2; ++i)
        #pragma unroll
        for (int j = 0; j < 8; ++j) acc[i][j] = {0.f, 0.f, 0.f, 0.f};

    uint4 apf[4], bpf[4];
    #pragma unroll
    for (int p = 0; p < 4; ++p) {
        apf[p] = *(const uint4*)(qh + (size_t)(n0 + br + p * 32) * 512 + bcs);
        bpf[p] = *(const uint4*)(kh + (size_t)(m0 + br + p * 32) * 512 + bcs);
    }
    #pragma unroll
    for (int p = 0; p < 4; ++p) {
        *(uint4*)&As[(br + p * 32) * 72 + bcs] = apf[p];
        *(uint4*)&Bs[(br + p * 32) * 72 + bcs] = bpf[p];
    }
    __syncthreads();

    for (int kc = 0; kc < 8; ++kc) {
        if (kc < 7) {
            #pragma unroll
            for (int p = 0; p < 4; ++p) {
                apf[p] = *(const uint4*)(qh + (size_t)(n0 + br + p * 32) * 512 + (kc + 1) * 64 + bcs);
                bpf[p] = *(const uint4*)(kh + (size_t)(m0 + br + p * 32) * 512 + (kc + 1) * 64 + bcs);
            }
        }
        #pragma unroll
        for (int kk = 0; kk < 2; ++kk) {
            short8 a0 = *(const short8*)&As[(wave * 32 + l16) * 72 + kk * 32 + quad * 8];
            short8 a1 = *(const short8*)&As[(wave * 32 + 16 + l16) * 72 + kk * 32 + quad * 8];
            #pragma unroll
            for (int ct = 0; ct < 8; ++ct) {
                short8 b = *(const short8*)&Bs[(ct * 16 + l16) * 72 + kk * 32 + quad * 8];
                acc[0][ct] = __builtin_amdgcn_mfma_f32_16x16x32_bf16(a0, b, acc[0][ct], 0, 0, 0);
                acc[1][ct] = __builtin_amdgcn_mfma_f32_16x16x32_bf16(a1, b, acc[1][ct], 0, 0, 0);
            }
        }
        if (kc < 7) {
            __syncthreads();
            #pragma unroll
            for (int p = 0; p < 4; ++p) {
                *(uint4*)&As[(br + p * 32) * 72 + bcs] = apf[p];
                *(uint4*)&Bs[(br + p * 32) * 72 + bcs] = bpf[p];
            }
            __syncthreads();
        }
    }

    float iq[2][4], ik[8], idm[8];
    #pragma unroll
    for (int rt = 0; rt < 2; ++rt)
        #pragma unroll
        for (int reg = 0; reg < 4; ++reg)
            iq[rt][reg] = rsqrtf(ssq[n0 + wave * 32 + rt * 16 + quad * 4 + reg]);
    #pragma unroll
    for (int ct = 0; ct < 8; ++ct) {
        ik[ct]  = rsqrtf(ssq[NE + m0 + ct * 16 + l16]);
        idm[ct] = rsqrtf(ssq[2 * NE + m0 + ct * 16 + l16]);
    }

    __syncthreads();   // As/Bs reads done; smem becomes Pl
    #pragma unroll
    for (int rt = 0; rt < 2; ++rt) {
        #pragma unroll
        for (int reg = 0; reg < 4; ++reg) {
            int nl = wave * 32 + rt * 16 + quad * 4 + reg;
            float qs = iq[rt][reg];
            float rs = 0.f;
            #pragma unroll
            for (int ct = 0; ct < 8; ++ct) {
                float e = __expf(acc[rt][ct][reg] * qs * ik[ct]);
                Pl[nl * 136 + ct * 16 + l16] = f2bf(e * idm[ct]);
                rs += e;
            }
            #pragma unroll
            for (int msk = 8; msk >= 1; msk >>= 1) rs += __shfl_xor(rs, msk, 16);
            if (l16 == 0) atomicAdd(&lbuf[(size_t)h * NE + n0 + nl], rs);
        }
    }
    __syncthreads();
    const int prow = t >> 1, phalf = (t & 1) * 64;
    unsigned short* dst = P + (size_t)hg * NE * NE + (size_t)(n0 + prow) * NE + m0 + phalf;
    const unsigned short* src = &Pl[prow * 136 + phalf];
    #pragma unroll
    for (int j = 0; j < 8; ++j)
        *(uint4*)(dst + j * 8) = *(const uint4*)(src + j * 8);
}

// ---------------------------------------------------------------------------
// K2b: V[n][f] = (sum_m P'[n][m] * dTu[f][m]) / l[n]
// 64n x 64f tile, BK=128 (16 iters), grid 1024 (4 blocks/CU), reg-prefetch.
// ---------------------------------------------------------------------------
__global__ __launch_bounds__(256) void combine_kernel(
    const unsigned short* __restrict__ P, const unsigned short* __restrict__ dTu,
    const float* __restrict__ lbuf, float* __restrict__ out, int g)
{
    __shared__ unsigned short smem[2 * 64 * 136];   // Ps | Ds ; re-used as V-tile
    unsigned short* Ps = smem;
    unsigned short* Ds = smem + 64 * 136;
    float* Vt = (float*)smem;                       // 64 x 68 fp32

    const int t = threadIdx.x;
    const int hg = blockIdx.z, h = g * 4 + hg;
    const int n0 = blockIdx.y * 64, f0 = blockIdx.x * 64;
    const int wave = t >> 6, lane = t & 63, quad = lane >> 4, l16 = lane & 15;
    const unsigned short* Ph = P + (size_t)hg * NE * NE;
    const unsigned short* dh = dTu + (size_t)h * 512 * NE;
    const int r2 = t >> 4, bcs2 = (t & 15) * 8;

    f32x4 acc[4];
    #pragma unroll
    for (int j = 0; j < 4; ++j) acc[j] = {0.f, 0.f, 0.f, 0.f};

    uint4 ppf[4], dpf[4];
    #pragma unroll
    for (int p = 0; p < 4; ++p) {
        ppf[p] = *(const uint4*)(Ph + (size_t)(n0 + r2 + p * 16) * NE + bcs2);
        dpf[p] = *(const uint4*)(dh + (size_t)(f0 + r2 + p * 16) * NE + bcs2);
    }
    #pragma unroll
    for (int p = 0; p < 4; ++p) {
        *(uint4*)&Ps[(r2 + p * 16) * 136 + bcs2] = ppf[p];
        *(uint4*)&Ds[(r2 + p * 16) * 136 + bcs2] = dpf[p];
    }
    __syncthreads();

    for (int mc = 0; mc < 16; ++mc) {
        if (mc < 15) {
            #pragma unroll
            for (int p = 0; p < 4; ++p) {
                ppf[p] = *(const uint4*)(Ph + (size_t)(n0 + r2 + p * 16) * NE + (mc + 1) * 128 + bcs2);
                dpf[p] = *(const uint4*)(dh + (size_t)(f0 + r2 + p * 16) * NE + (mc + 1) * 128 + bcs2);
            }
        }
        #pragma unroll
        for (int kk = 0; kk < 4; ++kk) {
            short8 a = *(const short8*)&Ps[(wave * 16 + l16) * 136 + kk * 32 + quad * 8];
            #pragma unroll
            for (int ct = 0; ct < 4; ++ct) {
                short8 b = *(const short8*)&Ds[(ct * 16 + l16) * 136 + kk * 32 + quad * 8];
                acc[ct] = __builtin_amdgcn_mfma_f32_16x16x32_bf16(a, b, acc[ct], 0, 0, 0);
            }
        }
        if (mc < 15) {
            __syncthreads();
            #pragma unroll
            for (int p = 0; p < 4; ++p) {
                *(uint4*)&Ps[(r2 + p * 16) * 136 + bcs2] = ppf[p];
                *(uint4*)&Ds[(r2 + p * 16) * 136 + bcs2] = dpf[p];
            }
            __syncthreads();
        }
    }
    __syncthreads();   // Ps/Ds reads done; smem becomes Vt
    const int nl = wave * 16 + quad * 4;
    #pragma unroll
    for (int reg = 0; reg < 4; ++reg)
        #pragma unroll
        for (int ct = 0; ct < 4; ++ct)
            Vt[(nl + reg) * 68 + ct * 16 + l16] = acc[ct][reg];
    __syncthreads();
    const int vrow = t >> 2, seg = t & 3;
    float inv = 1.0f / lbuf[(size_t)h * NE + n0 + vrow];
    float* orow = out + (size_t)(n0 + vrow) * 4096 + h * 512 + f0 + seg * 16;
    #pragma unroll
    for (int i = 0; i < 4; ++i) {
        float4 o;
        o.x = Vt[vrow * 68 + seg * 16 + i * 4 + 0] * inv;
        o.y = Vt[vrow * 68 + seg * 16 + i * 4 + 1] * inv;
        o.z = Vt[vrow * 68 + seg * 16 + i * 4 + 2] * inv;
        o.w = Vt[vrow * 68 + seg * 16 + i * 4 + 3] * inv;
        *(float4*)(orow + i * 4) = o;
    }
}

extern "C" void kernel_launch(void* const* d_in, const int* in_sizes, int n_in,
                              void* d_out, int out_size, void* d_ws, size_t ws_size,
                              hipStream_t stream)
{
    const float* x  = (const float*)d_in[0];
    const float* Qw = (const float*)d_in[1];
    const float* Kw = (const float*)d_in[2];
    const float* Dw = (const float*)d_in[3];
    float* out = (float*)d_out;

    // ws: xt 16M | qb 16M | kb 16M | dTu 16M | P 32M | ssq 24K | lbuf 64K  (~96.1 MB)
    char* ws = (char*)d_ws;
    unsigned short* xt  = (unsigned short*)ws;
    unsigned short* qb  = (unsigned short*)(ws + 1 * 16777216);
    unsigned short* kb  = (unsigned short*)(ws + 2 * 16777216);
    unsigned short* dTu = (unsigned short*)(ws + 3 * 16777216);
    unsigned short* P   = (unsigned short*)(ws + 4 * 16777216);
    float* ssq  = (float*)(ws + 6 * 16777216);
    float* lbuf = (float*)(ws + 6 * 16777216 + 24576);

    hipMemsetAsync(ssq, 0, 24576 + 65536, stream);
    xpose_kernel<<<2048, 256, 0, stream>>>(x, xt);
    proj_gemm<<<dim3(128, 4, 3), 256, 0, stream>>>(Qw, Kw, Dw, xt, qb, kb, dTu, ssq);
    for (int g = 0; g < 2; ++g) {
        score_kernel<<<dim3(16, 16, 4), 256, 0, stream>>>(qb, kb, ssq, P, lbuf, g);
        combine_kernel<<<dim3(8, 32, 4), 256, 0, stream>>>(P, dTu, lbuf, out, g);
    }
}